// Round 10
// baseline (1503.198 us; speedup 1.0000x reference)
//
#include <hip/hip_runtime.h>

// TemporalAttentionDecoder_three_step: B=512, T=64, M=P=256. in f32, out f32.
// R8 (1.5MB wt/CU/step) == R9 (0.77MB) == ~1.2ms  => NOT weight-BW-bound.
// Both ran 8 waves/CU (Occ 24%), VALU ~45%, all pipes <50% => latency-bound
// at low occupancy. R10: same r=2-rows/WG structure, 1024-thr WGs (256 WGs =
// 1/CU) => 16 waves/CU, half the per-thread work, 2x latency hiding.
// N-split: Whh thread<->row(1024); Wd/Wy k-quarters; B1 8 m-chunks/row;
// B2 t-halves. Ud prepped f16 k-blocked too (y1 build via fdot2).
// LDS ~99KB (y1 f16 in LDS; E16 f16 in ws). launch_bounds(1024,4) caps 128 VGPR.

typedef unsigned short u16;
typedef unsigned int u32;
typedef _Float16 half_t;
typedef half_t h2 __attribute__((ext_vector_type(2)));

#define BB 512
#define TT 64
#define MM 256
#define PP 256
#define YS 264   // y1l row stride (u16); measured conflict-free (R6-R9)

// ws layout (u16), weights k-blocked n-major [kb][n][8]:
#define WD16_OFF  0                    // [64][256][8]  131072
#define WHH16_OFF 131072               // [32][1024][8] 262144
#define WY16_OFF  393216               // [64][256][8]  131072
#define UD16_OFF  524288               // [32][256][8]  65536
#define WPREP_ELEMS 589824
#define E16_OFF   589824               // (B,T,M) row-major f16
#define E16_ELEMS (BB * TT * MM)
#define WS_ELEMS  (WPREP_ELEMS + E16_ELEMS)
#define WS_BYTES  ((size_t)WS_ELEMS * 2)

struct H8 { h2 p[4]; };   // 16B = 8 f16

#if defined(__has_builtin)
#if __has_builtin(__builtin_amdgcn_fdot2)
#define FDOT2(a, b, c) __builtin_amdgcn_fdot2((a), (b), (c), false)
#endif
#endif
#ifndef FDOT2
__device__ __forceinline__ float FDOT2(h2 a, h2 b, float c) {
  return c + (float)a[0] * (float)b[0] + (float)a[1] * (float)b[1];
}
#endif

__device__ __forceinline__ float dot8(const H8 w, const H8 a, float acc) {
  acc = FDOT2(w.p[0], a.p[0], acc);
  acc = FDOT2(w.p[1], a.p[1], acc);
  acc = FDOT2(w.p[2], a.p[2], acc);
  acc = FDOT2(w.p[3], a.p[3], acc);
  return acc;
}
__device__ __forceinline__ u16 f2h(float f) {
  union { half_t h; u16 u; } x; x.h = (half_t)f; return x.u;
}
__device__ __forceinline__ void unpackH8(const H8 v, float f[8]) {
#pragma unroll
  for (int i = 0; i < 8; ++i) f[i] = (float)v.p[i >> 1][i & 1];
}
__device__ __forceinline__ void ldf8(const float* p, float f[8]) {
  float4 a = *(const float4*)p;
  float4 b = *(const float4*)(p + 4);
  f[0]=a.x; f[1]=a.y; f[2]=a.z; f[3]=a.w;
  f[4]=b.x; f[5]=b.y; f[6]=b.z; f[7]=b.w;
}
__device__ __forceinline__ float tanh_fast(float x) {
  float e = __builtin_amdgcn_exp2f(x * 2.885390081777927f);
  return 1.0f - 2.0f * __builtin_amdgcn_rcpf(1.0f + e);
}
__device__ __forceinline__ float sigmoid_fast(float x) {
  float e = __builtin_amdgcn_exp2f(x * -1.4426950408889634f);
  return __builtin_amdgcn_rcpf(1.0f + e);
}

// ---- prep: weights (+Ud) f32 -> f16 k-blocked n-major ----
__global__ __launch_bounds__(256) void prep_w(
    const float* __restrict__ Wd, const float* __restrict__ Whh,
    const float* __restrict__ Wy, const float* __restrict__ Ud,
    u16* __restrict__ o) {
  int i = blockIdx.x * 256 + threadIdx.x;   // 0..589823
  float v;
  if (i < WHH16_OFF) {
    int ki = i & 7, n = (i >> 3) & 255, kb = i >> 11;
    v = Wd[n * 512 + kb * 8 + ki];
  } else if (i < WY16_OFF) {
    int r = i - WHH16_OFF;
    int ki = r & 7, n = (r >> 3) & 1023, kb = r >> 13;
    v = Whh[n * 256 + kb * 8 + ki];
  } else if (i < UD16_OFF) {
    int r = i - WY16_OFF;
    int ki = r & 7, n = (r >> 3) & 255, kb = r >> 11;
    v = Wy[n * 512 + kb * 8 + ki];
  } else {
    int r = i - UD16_OFF;
    int ki = r & 7, n = (r >> 3) & 255, kb = r >> 11;
    v = Ud[n * 256 + kb * 8 + ki];
  }
  o[i] = f2h(v);
}

// ---- prep: E f32 -> f16 row-major ----
__global__ __launch_bounds__(256) void prep_e(
    const float* __restrict__ E, u16* __restrict__ o) {
  int i = blockIdx.x * 256 + threadIdx.x;
  o[E16_OFF + i] = f2h(E[i]);
}

template <int WQ>
__global__ __launch_bounds__(1024, 4) void scan_kernel(
    const float* __restrict__ E,      // (B,T,M) f32
    const float* __restrict__ yin,    // (B,T,1)
    const float* __restrict__ tar,    // (B,2)
    const int*   __restrict__ train,  // (1)
    const void*  __restrict__ Wd_q,   // WQ1: f16 k-blocked | WQ0: f32 row-major
    const float* __restrict__ Wd_b,
    const void*  __restrict__ Ud_q,   // WQ1: f16 k-blocked | WQ0: f32 row-major
    const float* __restrict__ vd_w,
    const float* __restrict__ wt_w,   // (257)
    const float* __restrict__ wt_b,
    const void*  __restrict__ Wy_q,
    const float* __restrict__ Wy_b,
    const float* __restrict__ vy_w,
    const float* __restrict__ vy_b,
    const float* __restrict__ Wih,    // (1024)
    const void*  __restrict__ Whh_q,
    const float* __restrict__ bih,
    const float* __restrict__ bhh,
    const u16*   __restrict__ E16,    // f16 (B,T,M) in ws (WQ1 only)
    float* __restrict__ out)          // (3*B)
{
  __shared__ __align__(16) u16   y1l[2][TT * YS];   // 67.6KB f16 y1, padded
  __shared__ __align__(16) u32   hs16[2][256];      // h pairs[0,128) c[128,256)
  __shared__ __align__(16) u32   ctx16p[2][128];    // ct f16 pairs
  __shared__ __align__(16) float ctx[2][256];
  __shared__ __align__(16) float x1s[2][256];
  __shared__ __align__(16) float part[4][2][256];   // k-quarter partials
  __shared__ __align__(16) float part2[2][2][256];  // B2 t-half partials
  __shared__ __align__(16) float gbuf[2][1024];     // Whh matvec
  __shared__ __align__(16) float lpart[2][8][64];
  __shared__ float red[2][4], red2[2][4];
  __shared__ float sc_head[2];

  const int tid  = threadIdx.x;        // 0..1023
  const int lane = tid & 63;
  const int w    = tid >> 6;           // wave 0..15
  // stream/head mapping
  const int n    = tid & 255;
  const int kq   = tid >> 8;           // k-quarter 0..3
  // combine/gates mapping (waves 0..7)
  const int rw   = w >> 2;             // row
  const int jj   = (w & 3) * 64 + lane;
  // B1 mapping
  const int r1   = w >> 3;
  const int mq   = w & 7;              // 32-wide m chunk
  // B2 mapping
  const int kh   = (w >> 2) & 1;       // t-half
  const int j2   = (w & 3) * 64 + lane;

  if (tid < 512) ((u32*)hs16)[tid] = 0;
  float creg = 0.f;

  // ---- y1 into LDS: thread (j=n, group kq: row=kq>>1, thalf=kq&1) ----
  {
    const int yr  = kq >> 1;
    const int th  = kq & 1;
    const int bb  = blockIdx.x * 2 + yr;
    if (WQ) {
      const half_t* __restrict__ Ef = (const half_t*)E16;
      for (int t = th * 32; t < th * 32 + 32; ++t) {
        const half_t* ee = Ef + ((size_t)bb * TT + t) * MM;
        const u16* pu = (const u16*)Ud_q + (size_t)n * 8;
        float acc = 0.f;
#pragma unroll 8
        for (int kb = 0; kb < 32; ++kb) {
          H8 uw = *(const H8*)pu; pu += 2048;
          H8 ev = *(const H8*)(ee + kb * 8);
          acc = dot8(uw, ev, acc);
        }
        y1l[yr][t * YS + n] = f2h(acc);
      }
    } else {
      const float* __restrict__ Eb = E + (size_t)bb * TT * MM;
      const float* __restrict__ Uj = (const float*)Ud_q + (size_t)n * MM;
      for (int t = th * 32; t < th * 32 + 32; ++t) {
        float acc = 0.f;
        for (int m0 = 0; m0 < MM; m0 += 8) {
          float uu[8], ee[8];
          ldf8(Uj + m0, uu);
          ldf8(Eb + (size_t)t * MM + m0, ee);
#pragma unroll
          for (int i = 0; i < 8; ++i) acc = fmaf(uu[i], ee[i], acc);
        }
        y1l[yr][t * YS + n] = f2h(acc);
      }
    }
  }
  __syncthreads();

  // ---- Whh @ h for BOTH rows, thread <-> row n=tid (weights loaded once) ----
  auto whh_mv = [&]() {
    float b0 = 0.f, b1 = 0.f;
    if (WQ) {
      const u16* ph = (const u16*)Whh_q + (size_t)tid * 8;
#pragma unroll 8
      for (int kb = 0; kb < 32; ++kb) {
        H8 w8 = *(const H8*)ph; ph += 8192;
        b0 = dot8(w8, *(const H8*)&hs16[0][kb * 4], b0);
        b1 = dot8(w8, *(const H8*)&hs16[1][kb * 4], b1);
      }
    } else {
      const float* ph = (const float*)Whh_q + (size_t)tid * 256;
#pragma unroll 4
      for (int kb = 0; kb < 32; ++kb) {
        float w8[8]; ldf8(ph + kb * 8, w8);
        float f0[8], f1[8];
        unpackH8(*(const H8*)&hs16[0][kb * 4], f0);
        unpackH8(*(const H8*)&hs16[1][kb * 4], f1);
#pragma unroll
        for (int i = 0; i < 8; ++i) {
          b0 = fmaf(f0[i], w8[i], b0);
          b1 = fmaf(f1[i], w8[i], b1);
        }
      }
    }
    gbuf[0][tid] = b0;
    gbuf[1][tid] = b1;
  };

  // ---- gates (waves 0..7, thread (rw, jj)) ----
  auto gates_apply = [&](float ytil) {
    float g0 = gbuf[rw][jj]       + ytil * Wih[jj]       + bih[jj]       + bhh[jj];
    float g1 = gbuf[rw][jj + 256] + ytil * Wih[jj + 256] + bih[jj + 256] + bhh[jj + 256];
    float g2 = gbuf[rw][jj + 512] + ytil * Wih[jj + 512] + bih[jj + 512] + bhh[jj + 512];
    float g3 = gbuf[rw][jj + 768] + ytil * Wih[jj + 768] + bih[jj + 768] + bhh[jj + 768];
    float c = sigmoid_fast(g1) * creg + sigmoid_fast(g0) * tanh_fast(g2);
    float h = sigmoid_fast(g3) * tanh_fast(c);
    creg = c;
    ((u16*)&hs16[rw][0])[jj]       = f2h(h);
    ((u16*)&hs16[rw][0])[256 + jj] = f2h(c);
  };

  // ---- head: thread (n, kq); act = h (kq<2) else ct ----
  auto head_store = [&](int outIdx) {
    float p0 = 0.f, p1 = 0.f;
    if (WQ) {
      const u16* pw = (const u16*)Wy_q + ((size_t)(kq * 16) * 256 + n) * 8;
      const u32* a0 = (kq < 2) ? &hs16[0][kq * 64] : &ctx16p[0][(kq - 2) * 64];
      const u32* a1 = (kq < 2) ? &hs16[1][kq * 64] : &ctx16p[1][(kq - 2) * 64];
#pragma unroll 8
      for (int i = 0; i < 16; ++i) {
        H8 w8 = *(const H8*)pw; pw += 2048;
        p0 = dot8(w8, *(const H8*)&a0[i * 4], p0);
        p1 = dot8(w8, *(const H8*)&a1[i * 4], p1);
      }
    } else {
      const float* pw = (const float*)Wy_q + (size_t)n * 512 + kq * 128;
      for (int i = 0; i < 16; ++i) {
        float w8[8]; ldf8(pw + i * 8, w8);
        int kb = kq * 16 + i;
        float f0[8], f1[8];
        if (kb < 32) {
          unpackH8(*(const H8*)&hs16[0][kb * 4], f0);
          unpackH8(*(const H8*)&hs16[1][kb * 4], f1);
        } else {
          ldf8(&ctx[0][(kb - 32) * 8], f0);
          ldf8(&ctx[1][(kb - 32) * 8], f1);
        }
#pragma unroll
        for (int i2 = 0; i2 < 8; ++i2) {
          p0 = fmaf(f0[i2], w8[i2], p0);
          p1 = fmaf(f1[i2], w8[i2], p1);
        }
      }
    }
    part[kq][0][n] = p0;
    part[kq][1][n] = p1;
    __syncthreads();
    if (w < 8) {
      float hp = part[0][rw][jj] + part[1][rw][jj] + part[2][rw][jj]
               + part[3][rw][jj] + Wy_b[jj];
      float pp = hp * vy_w[jj];
#pragma unroll
      for (int off = 32; off; off >>= 1) pp += __shfl_xor(pp, off, 64);
      if (lane == 0) red[rw][w & 3] = pp;
    }
    __syncthreads();
    if (w < 8 && (w & 3) == 0 && lane == 0) {
      float o = red[rw][0] + red[rw][1] + red[rw][2] + red[rw][3] + vy_b[0];
      out[(size_t)outIdx * BB + blockIdx.x * 2 + rw] = o;
      sc_head[rw] = o;
    }
    __syncthreads();
  };

  // ================= scan over T steps =================
  for (int step = 0; step < TT; ++step) {
    // ---- stream: Wd k-quarter (both rows, weight once) + Whh row (both) ----
    {
      float ax0 = 0.f, ax1 = 0.f;
      if (WQ) {
        const u16* pd = (const u16*)Wd_q + ((size_t)(kq * 16) * 256 + n) * 8;
        const u32* a0 = (kq < 2) ? &hs16[0][kq * 64] : &hs16[0][128 + (kq - 2) * 64];
        const u32* a1 = (kq < 2) ? &hs16[1][kq * 64] : &hs16[1][128 + (kq - 2) * 64];
#pragma unroll 8
        for (int i = 0; i < 16; ++i) {
          H8 w8 = *(const H8*)pd; pd += 2048;
          ax0 = dot8(w8, *(const H8*)&a0[i * 4], ax0);
          ax1 = dot8(w8, *(const H8*)&a1[i * 4], ax1);
        }
      } else {
        const float* pd = (const float*)Wd_q + (size_t)n * 512 + kq * 128;
        const u32* a0 = (kq < 2) ? &hs16[0][kq * 64] : &hs16[0][128 + (kq - 2) * 64];
        const u32* a1 = (kq < 2) ? &hs16[1][kq * 64] : &hs16[1][128 + (kq - 2) * 64];
        for (int i = 0; i < 16; ++i) {
          float w8[8]; ldf8(pd + i * 8, w8);
          float f0[8], f1[8];
          unpackH8(*(const H8*)&a0[i * 4], f0);
          unpackH8(*(const H8*)&a1[i * 4], f1);
#pragma unroll
          for (int i2 = 0; i2 < 8; ++i2) {
            ax0 = fmaf(f0[i2], w8[i2], ax0);
            ax1 = fmaf(f1[i2], w8[i2], ax1);
          }
        }
      }
      part[kq][0][n] = ax0;
      part[kq][1][n] = ax1;
      whh_mv();
    }
    __syncthreads();

    // ---- C1: x1 combine (waves 0..7) ----
    if (w < 8) {
      x1s[rw][jj] = part[0][rw][jj] + part[1][rw][jj] + part[2][rw][jj]
                  + part[3][rw][jj] + Wd_b[jj];
    }
    __syncthreads();

    // ---- B1: lpart[r1][mq][t=lane], 32 m-elems each ----
    {
      const u16* __restrict__ yrow = &y1l[r1][lane * YS + mq * 32];
      const float* __restrict__ xp = &x1s[r1][mq * 32];
      const float* __restrict__ vp = vd_w + mq * 32;
      float lp = 0.f;
#pragma unroll
      for (int m0 = 0; m0 < 32; m0 += 8) {
        H8 yv = *(const H8*)(yrow + m0);
        float yf[8]; unpackH8(yv, yf);
        float xf[8]; ldf8(xp + m0, xf);
        float vf[8]; ldf8(vp + m0, vf);
#pragma unroll
        for (int mm = 0; mm < 8; ++mm) {
          float z = tanh_fast(xf[mm] + yf[mm]);
          lp = fmaf(z, vf[mm], lp);
        }
      }
      lpart[r1][mq][lane] = lp;
    }
    __syncthreads();

    // ---- SM+B2: every wave computes its row's softmax; B2 t-half ----
    {
      float l = 0.f;
#pragma unroll
      for (int q = 0; q < 8; ++q) l += lpart[r1][q][lane];
      float mx = l;
#pragma unroll
      for (int off = 32; off; off >>= 1) mx = fmaxf(mx, __shfl_xor(mx, off, 64));
      float e = __builtin_amdgcn_exp2f((l - mx) * 1.4426950408889634f);
      float sm = e;
#pragma unroll
      for (int off = 32; off; off >>= 1) sm += __shfl_xor(sm, off, 64);
      float beta = e * __builtin_amdgcn_rcpf(sm);   // lane t's beta, row r1

      const int bb = blockIdx.x * 2 + r1;
      float acc = 0.f;
      if (WQ) {
        const half_t* __restrict__ ep =
            (const half_t*)E16 + ((size_t)bb * TT + kh * 32) * MM + j2;
#pragma unroll 8
        for (int i = 0; i < 32; ++i) {
          float bt = __shfl(beta, kh * 32 + i, 64);
          acc = fmaf(bt, (float)ep[(size_t)i * MM], acc);
        }
      } else {
        const float* __restrict__ ep =
            E + ((size_t)bb * TT + kh * 32) * MM + j2;
#pragma unroll 8
        for (int i = 0; i < 32; ++i) {
          float bt = __shfl(beta, kh * 32 + i, 64);
          acc = fmaf(bt, ep[(size_t)i * MM], acc);
        }
      }
      part2[r1][kh][j2] = acc;
    }
    __syncthreads();

    // ---- C2: ct combine + ytil partial (waves 0..7) ----
    if (w < 8) {
      float ct = part2[rw][0][jj] + part2[rw][1][jj];
      ctx[rw][jj] = ct;
      ((u16*)&ctx16p[rw][0])[jj] = f2h(ct);
      float p = ct * wt_w[jj];
#pragma unroll
      for (int off = 32; off; off >>= 1) p += __shfl_xor(p, off, 64);
      if (lane == 0) red[rw][w & 3] = p;
    }
    __syncthreads();

    // ---- gates ----
    if (w < 8) {
      const int bb = blockIdx.x * 2 + rw;
      float ytil = red[rw][0] + red[rw][1] + red[rw][2] + red[rw][3]
                 + yin[(size_t)bb * TT + step] * wt_w[MM] + wt_b[0];
      gates_apply(ytil);
    }
    __syncthreads();
  }

  // ================= finals =================
  if (w < 8) {
    float p = ctx[rw][jj] * wt_w[jj];
#pragma unroll
    for (int off = 32; off; off >>= 1) p += __shfl_xor(p, off, 64);
    if (lane == 0) red2[rw][w & 3] = p;
  }
  __syncthreads();

  head_store(0);  // y_Tp1 (sc_head[row] holds it for train==0 feedback)

  const int tr = train[0];
  for (int e = 0; e < 2; ++e) {
    whh_mv();
    __syncthreads();
    if (w < 8) {
      const int bb = blockIdx.x * 2 + rw;
      float inp = tr ? tar[(size_t)bb * 2 + e] : sc_head[rw];
      float ytil = red2[rw][0] + red2[rw][1] + red2[rw][2] + red2[rw][3]
                 + inp * wt_w[MM] + wt_b[0];
      gates_apply(ytil);
    }
    __syncthreads();
    head_store(1 + e);
  }
}

extern "C" void kernel_launch(void* const* d_in, const int* in_sizes, int n_in,
                              void* d_out, int out_size, void* d_ws, size_t ws_size,
                              hipStream_t stream) {
  const float* E     = (const float*)d_in[0];
  const float* yin   = (const float*)d_in[1];
  const float* tar   = (const float*)d_in[2];
  const int*   train = (const int*)d_in[3];
  const float* Wd_w  = (const float*)d_in[4];
  const float* Wd_b  = (const float*)d_in[5];
  const float* Ud_w  = (const float*)d_in[6];
  const float* vd_w  = (const float*)d_in[7];
  const float* wt_w  = (const float*)d_in[8];
  const float* wt_b  = (const float*)d_in[9];
  const float* Wy_w  = (const float*)d_in[10];
  const float* Wy_b  = (const float*)d_in[11];
  const float* vy_w  = (const float*)d_in[12];
  const float* vy_b  = (const float*)d_in[13];
  const float* Wih   = (const float*)d_in[14];
  const float* Whh   = (const float*)d_in[15];
  const float* bih   = (const float*)d_in[16];
  const float* bhh   = (const float*)d_in[17];

  float* out = (float*)d_out;

  if (ws_size >= WS_BYTES) {
    u16* wq = (u16*)d_ws;
    prep_w<<<dim3(WPREP_ELEMS / 256), dim3(256), 0, stream>>>(
        Wd_w, Whh, Wy_w, Ud_w, wq);
    prep_e<<<dim3(E16_ELEMS / 256), dim3(256), 0, stream>>>(E, wq);
    scan_kernel<1><<<dim3(BB / 2), dim3(1024), 0, stream>>>(
        E, yin, tar, train, wq + WD16_OFF, Wd_b, wq + UD16_OFF, vd_w, wt_w,
        wt_b, wq + WY16_OFF, Wy_b, vy_w, vy_b, Wih, wq + WHH16_OFF, bih, bhh,
        wq + E16_OFF, out);
  } else {
    scan_kernel<0><<<dim3(BB / 2), dim3(1024), 0, stream>>>(
        E, yin, tar, train, Wd_w, Wd_b, Ud_w, vd_w, wt_w, wt_b,
        Wy_w, Wy_b, vy_w, vy_b, Wih, Whh, bih, bhh, (const u16*)nullptr, out);
  }

  (void)in_sizes; (void)n_in; (void)out_size;
}

// Round 11
// 1199.846 us; speedup vs baseline: 1.2528x; 1.2528x over previous
//
#include <hip/hip_runtime.h>

// TemporalAttentionDecoder_three_step: B=512, T=64, M=P=256. in f32, out f32.
// Evidence: R8(8w/CU,2WG)=1189us, R9(half weight bytes)=1195, R10(16w/CU)=1503
//   -> not weight-BW, not occupancy, not conflicts. ~46Kcyc/step vs ~8K work
//   => barrier-serialized phase chain is the cost.
// R11 = R8 architecture with 2 barriers/step (was 5):
//   - stream->B1 barrier dropped: wave q reads only the x1 quarter it wrote.
//   - SM+B2+ytil+gates fused barrier-free: per-wave redundant softmax,
//     wave-private betas copy (same-wave RAW), each lane computes ct for
//     m=q*64+lane (all q) so ytil reduces in-wave; gates use register g0..g3.
//   - lpart barrier doubles as hs16 read/write separator.
//   - extra-step mv/gates race (latent in R8) fixed with explicit barrier.
// 256 thr/WG, 1 row/WG, 512 WGs, 2 WG/CU (LDS ~74KB). f16 k-blocked weights.

typedef unsigned short u16;
typedef unsigned int u32;
typedef _Float16 half_t;
typedef half_t h2 __attribute__((ext_vector_type(2)));

#define BB 512
#define TT 64
#define MM 256
#define PP 256
#define YS 264   // y1l row stride (u16); measured conflict-free (R6-R10)
#define ES 68    // e16T row stride (u16); measured conflict-free (R8)

// ws layout (u16), weights k-blocked n-major [kb][n][8]:
#define WD16_OFF  0          // [64][256][8]  131072
#define WHH16_OFF 131072     // [32][1024][8] 262144
#define WY16_OFF  393216     // [64][256][8]  131072
#define WQ_ELEMS  524288
#define WQ_BYTES  ((size_t)WQ_ELEMS * 2)

struct H8 { h2 p[4]; };   // 16B = 8 f16

#if defined(__has_builtin)
#if __has_builtin(__builtin_amdgcn_fdot2)
#define FDOT2(a, b, c) __builtin_amdgcn_fdot2((a), (b), (c), false)
#endif
#endif
#ifndef FDOT2
__device__ __forceinline__ float FDOT2(h2 a, h2 b, float c) {
  return c + (float)a[0] * (float)b[0] + (float)a[1] * (float)b[1];
}
#endif

__device__ __forceinline__ float dot8(const H8 w, const H8 a, float acc) {
  acc = FDOT2(w.p[0], a.p[0], acc);
  acc = FDOT2(w.p[1], a.p[1], acc);
  acc = FDOT2(w.p[2], a.p[2], acc);
  acc = FDOT2(w.p[3], a.p[3], acc);
  return acc;
}
__device__ __forceinline__ u16 f2h(float f) {
  union { half_t h; u16 u; } x; x.h = (half_t)f; return x.u;
}
__device__ __forceinline__ void unpackH8(const H8 v, float f[8]) {
#pragma unroll
  for (int i = 0; i < 8; ++i) f[i] = (float)v.p[i >> 1][i & 1];
}
__device__ __forceinline__ void ldf8(const float* p, float f[8]) {
  float4 a = *(const float4*)p;
  float4 b = *(const float4*)(p + 4);
  f[0]=a.x; f[1]=a.y; f[2]=a.z; f[3]=a.w;
  f[4]=b.x; f[5]=b.y; f[6]=b.z; f[7]=b.w;
}
__device__ __forceinline__ float tanh_fast(float x) {
  float e = __builtin_amdgcn_exp2f(x * 2.885390081777927f);
  return 1.0f - 2.0f * __builtin_amdgcn_rcpf(1.0f + e);
}
__device__ __forceinline__ float sigmoid_fast(float x) {
  float e = __builtin_amdgcn_exp2f(x * -1.4426950408889634f);
  return __builtin_amdgcn_rcpf(1.0f + e);
}

// ---- prep: weights f32 -> f16 k-blocked n-major ----
__global__ __launch_bounds__(256) void prep_w(
    const float* __restrict__ Wd, const float* __restrict__ Whh,
    const float* __restrict__ Wy, u16* __restrict__ o) {
  int i = blockIdx.x * 256 + threadIdx.x;   // 0..524287
  float v;
  if (i < WHH16_OFF) {
    int ki = i & 7, n = (i >> 3) & 255, kb = i >> 11;
    v = Wd[n * 512 + kb * 8 + ki];
  } else if (i < WY16_OFF) {
    int r = i - WHH16_OFF;
    int ki = r & 7, n = (r >> 3) & 1023, kb = r >> 13;
    v = Whh[n * 256 + kb * 8 + ki];
  } else {
    int r = i - WY16_OFF;
    int ki = r & 7, n = (r >> 3) & 255, kb = r >> 11;
    v = Wy[n * 512 + kb * 8 + ki];
  }
  o[i] = f2h(v);
}

template <int WQ>
__global__ __launch_bounds__(256, 2) void scan_kernel(
    const float* __restrict__ E,      // (B,T,M) f32
    const float* __restrict__ yin,    // (B,T,1)
    const float* __restrict__ tar,    // (B,2)
    const int*   __restrict__ train,  // (1)
    const void*  __restrict__ Wd_q,   // WQ1: f16 k-blocked | WQ0: f32 row-major
    const float* __restrict__ Wd_b,
    const float* __restrict__ Ud_w,   // (256,256) f32
    const float* __restrict__ vd_w,
    const float* __restrict__ wt_w,   // (257)
    const float* __restrict__ wt_b,
    const void*  __restrict__ Wy_q,
    const float* __restrict__ Wy_b,
    const float* __restrict__ vy_w,
    const float* __restrict__ vy_b,
    const float* __restrict__ Wih,    // (1024)
    const void*  __restrict__ Whh_q,
    const float* __restrict__ bih,
    const float* __restrict__ bhh,
    float* __restrict__ out)          // (3*B)
{
  __shared__ __align__(16) u16   y1l[TT * YS];     // 33.8KB f16 y1, padded
  __shared__ __align__(16) u16   e16T[MM * ES];    // 34.8KB f16 E^T, padded
  __shared__ __align__(16) u32   hs16[256];        // h pairs[0,128) c[128,256)
  __shared__ __align__(16) u32   ctx16p[128];      // ct f16 pairs
  __shared__ __align__(16) float ctx[MM];
  __shared__ __align__(16) float x1s[MM];
  __shared__ __align__(16) float lpart[4][TT];
  __shared__ __align__(16) u16   betas_w[4 * TT];  // per-wave private copies
  __shared__ float red[4], red2[4];
  __shared__ float sc_head[1];

  const int j    = threadIdx.x;        // 0..255
  const int b    = blockIdx.x;
  const int wv   = j >> 6;
  const int lane = j & 63;

  hs16[j] = 0;
  float creg = 0.f;

  // ---- stage E^T (f16) into LDS ----
  {
    const float* __restrict__ Eb = E + (size_t)b * TT * MM;
    for (int i = j; i < TT * MM; i += 256) {
      int t = i >> 8, m = i & 255;
      e16T[m * ES + t] = f2h(Eb[i]);
    }
  }

  // ---- y1 into LDS: thread j computes column j for all 64 t (f32 math) ----
  {
    const float* __restrict__ Eb = E + (size_t)b * TT * MM;
    const float* __restrict__ Uj = Ud_w + (size_t)j * MM;
    for (int t0 = 0; t0 < TT; t0 += 16) {
      float acc[16];
#pragma unroll
      for (int i = 0; i < 16; ++i) acc[i] = 0.f;
      for (int m0 = 0; m0 < MM; m0 += 8) {
        float w[8]; ldf8(Uj + m0, w);
#pragma unroll
        for (int tt = 0; tt < 16; ++tt) {
          float e[8]; ldf8(Eb + (size_t)(t0 + tt) * MM + m0, e);
#pragma unroll
          for (int mm = 0; mm < 8; ++mm) acc[tt] = fmaf(e[mm], w[mm], acc[tt]);
        }
      }
#pragma unroll
      for (int tt = 0; tt < 16; ++tt)
        y1l[(t0 + tt) * YS + j] = f2h(acc[tt]);
    }
  }
  __syncthreads();

  // ---- Whh @ h -> 4 gate pre-activations in registers ----
  auto whh_mv = [&](float& g0, float& g1, float& g2, float& g3) {
    g0 = g1 = g2 = g3 = 0.f;
    if (WQ) {
      const u16* p0 = (const u16*)Whh_q + (size_t)j * 8;
      const u16* p1 = p0 + 256 * 8;
      const u16* p2 = p0 + 512 * 8;
      const u16* p3 = p0 + 768 * 8;
#pragma unroll 4
      for (int kb = 0; kb < 32; ++kb) {
        H8 hp = *(const H8*)&hs16[kb * 4];
        g0 = dot8(*(const H8*)p0, hp, g0); p0 += 8192;
        g1 = dot8(*(const H8*)p1, hp, g1); p1 += 8192;
        g2 = dot8(*(const H8*)p2, hp, g2); p2 += 8192;
        g3 = dot8(*(const H8*)p3, hp, g3); p3 += 8192;
      }
    } else {
      const float* p0 = (const float*)Whh_q + (size_t)j * 256;
#pragma unroll 2
      for (int kb = 0; kb < 32; ++kb) {
        H8 hp = *(const H8*)&hs16[kb * 4];
        float hf[8]; unpackH8(hp, hf);
        float w0[8], w1[8], w2[8], w3[8];
        ldf8(p0 + kb * 8, w0);
        ldf8(p0 + 256 * 256 + kb * 8, w1);
        ldf8(p0 + 512 * 256 + kb * 8, w2);
        ldf8(p0 + 768 * 256 + kb * 8, w3);
#pragma unroll
        for (int i = 0; i < 8; ++i) {
          g0 = fmaf(hf[i], w0[i], g0);
          g1 = fmaf(hf[i], w1[i], g1);
          g2 = fmaf(hf[i], w2[i], g2);
          g3 = fmaf(hf[i], w3[i], g3);
        }
      }
    }
  };

  // ---- gates: torch LSTMCell order i,f,g,o; writes h,c f16 to hs16 ----
  auto gates_apply = [&](float g0, float g1, float g2, float g3, float ytil) {
    g0 += ytil * Wih[j]       + bih[j]       + bhh[j];
    g1 += ytil * Wih[j + 256] + bih[j + 256] + bhh[j + 256];
    g2 += ytil * Wih[j + 512] + bih[j + 512] + bhh[j + 512];
    g3 += ytil * Wih[j + 768] + bih[j + 768] + bhh[j + 768];
    float c = sigmoid_fast(g1) * creg + sigmoid_fast(g0) * tanh_fast(g2);
    float h = sigmoid_fast(g3) * tanh_fast(c);
    creg = c;
    u16* hsu = (u16*)hs16;
    hsu[j]       = f2h(h);
    hsu[256 + j] = f2h(c);
  };

  // ---- head: ((concat[h,ct] @ Wy^T + b).vy + b) -> out, sc_head ----
  auto head_store = [&](int outIdx) {
    float p = 0.f;
    if (WQ) {
      const u16* ph = (const u16*)Wy_q + (size_t)j * 8;              // h seg
      const u16* pc = (const u16*)Wy_q + (size_t)(32 * 256 + j) * 8; // ct seg
#pragma unroll 4
      for (int kb = 0; kb < 32; ++kb) {
        H8 hp = *(const H8*)&hs16[kb * 4];
        H8 cp = *(const H8*)&ctx16p[kb * 4];
        p = dot8(*(const H8*)ph, hp, p); ph += 2048;
        p = dot8(*(const H8*)pc, cp, p); pc += 2048;
      }
    } else {
      const float* W = (const float*)Wy_q + (size_t)j * 512;
      for (int kb = 0; kb < 32; ++kb) {
        H8 hp = *(const H8*)&hs16[kb * 4];
        float hf[8]; unpackH8(hp, hf);
        float w0[8], w1[8];
        ldf8(W + kb * 8, w0);
        ldf8(W + 256 + kb * 8, w1);
#pragma unroll
        for (int i = 0; i < 8; ++i) {
          p = fmaf(hf[i], w0[i], p);
          p = fmaf(ctx[kb * 8 + i], w1[i], p);
        }
      }
    }
    float pp = (p + Wy_b[j]) * vy_w[j];
#pragma unroll
    for (int off = 32; off; off >>= 1) pp += __shfl_xor(pp, off, 64);
    if (lane == 0) red[wv] = pp;
    __syncthreads();
    if (j == 0) {
      float o = red[0] + red[1] + red[2] + red[3] + vy_b[0];
      out[(size_t)outIdx * BB + b] = o;
      sc_head[0] = o;
    }
    __syncthreads();
  };

  // ================= scan over T steps: 2 barriers/step =================
  for (int step = 0; step < TT; ++step) {
    // ---- stream: x1[j] (Wd) + g0..g3 (Whh), 6 dot streams ----
    float g0, g1, g2, g3;
    {
      float ax0 = 0.f, ax1 = 0.f;
      if (WQ) {
        const u16* pdh = (const u16*)Wd_q + (size_t)j * 8;              // h seg
        const u16* pdc = (const u16*)Wd_q + (size_t)(32 * 256 + j) * 8; // c seg
        const u16* p0 = (const u16*)Whh_q + (size_t)j * 8;
        const u16* p1 = p0 + 256 * 8;
        const u16* p2 = p0 + 512 * 8;
        const u16* p3 = p0 + 768 * 8;
        float b0 = 0.f, b1 = 0.f, b2 = 0.f, b3 = 0.f;
#pragma unroll 4
        for (int kb = 0; kb < 32; ++kb) {
          H8 hp = *(const H8*)&hs16[kb * 4];
          H8 cp = *(const H8*)&hs16[128 + kb * 4];
          ax0 = dot8(*(const H8*)pdh, hp, ax0); pdh += 2048;
          ax1 = dot8(*(const H8*)pdc, cp, ax1); pdc += 2048;
          b0 = dot8(*(const H8*)p0, hp, b0); p0 += 8192;
          b1 = dot8(*(const H8*)p1, hp, b1); p1 += 8192;
          b2 = dot8(*(const H8*)p2, hp, b2); p2 += 8192;
          b3 = dot8(*(const H8*)p3, hp, b3); p3 += 8192;
        }
        g0 = b0; g1 = b1; g2 = b2; g3 = b3;
      } else {
        const float* wd = (const float*)Wd_q + (size_t)j * 512;
        const float* w0p = (const float*)Whh_q + (size_t)j * 256;
        float b0 = 0.f, b1 = 0.f, b2 = 0.f, b3 = 0.f;
#pragma unroll 2
        for (int kb = 0; kb < 32; ++kb) {
          H8 hp = *(const H8*)&hs16[kb * 4];
          H8 cp = *(const H8*)&hs16[128 + kb * 4];
          float hf[8], cf[8]; unpackH8(hp, hf); unpackH8(cp, cf);
          float wh[8], wc[8], w0[8], w1[8], w2[8], w3[8];
          ldf8(wd + kb * 8, wh);
          ldf8(wd + 256 + kb * 8, wc);
          ldf8(w0p + kb * 8, w0);
          ldf8(w0p + 256 * 256 + kb * 8, w1);
          ldf8(w0p + 512 * 256 + kb * 8, w2);
          ldf8(w0p + 768 * 256 + kb * 8, w3);
#pragma unroll
          for (int i = 0; i < 8; ++i) {
            ax0 = fmaf(hf[i], wh[i], ax0);
            ax1 = fmaf(cf[i], wc[i], ax1);
            b0 = fmaf(hf[i], w0[i], b0);
            b1 = fmaf(hf[i], w1[i], b1);
            b2 = fmaf(hf[i], w2[i], b2);
            b3 = fmaf(hf[i], w3[i], b3);
          }
        }
        g0 = b0; g1 = b1; g2 = b2; g3 = b3;
      }
      x1s[j] = ax0 + ax1 + Wd_b[j];   // wave-private quarter (read by B1 below)
    }

    // ---- B1 (NO barrier: wave wv reads only the x1 quarter it wrote) ----
    {
      const u16* __restrict__ yrow = &y1l[lane * YS + wv * 64];
      const float* __restrict__ xp = &x1s[wv * 64];
      const float* __restrict__ vp = vd_w + wv * 64;
      float lp = 0.f;
#pragma unroll 2
      for (int m0 = 0; m0 < 64; m0 += 8) {
        H8 yv = *(const H8*)(yrow + m0);
        float yf[8]; unpackH8(yv, yf);
        float xf[8]; ldf8(xp + m0, xf);
        float vf[8]; ldf8(vp + m0, vf);
#pragma unroll
        for (int mm = 0; mm < 8; ++mm) {
          float z = tanh_fast(xf[mm] + yf[mm]);
          lp = fmaf(z, vf[mm], lp);
        }
      }
      lpart[wv][lane] = lp;
    }
    __syncthreads();   // [1] lpart ready; also separates hs16 reads from writes

    // ---- SM (per-wave redundant) + B2 + ytil (in-wave) + gates ----
    {
      float l = lpart[0][lane] + lpart[1][lane]
              + lpart[2][lane] + lpart[3][lane];
      float mx = l;
#pragma unroll
      for (int off = 32; off; off >>= 1) mx = fmaxf(mx, __shfl_xor(mx, off, 64));
      float e = __builtin_amdgcn_exp2f((l - mx) * 1.4426950408889634f);
      float sm = e;
#pragma unroll
      for (int off = 32; off; off >>= 1) sm += __shfl_xor(sm, off, 64);
      float beta = e * __builtin_amdgcn_rcpf(sm);   // lane t's beta
      betas_w[wv * 64 + lane] = f2h(beta);          // wave-private copy (in-order DS)

      // B2: lane computes ct[m] for m = q*64+lane, q=0..3 (all quarters)
      float ct[4];
#pragma unroll
      for (int q = 0; q < 4; ++q) {
        const u16* __restrict__ ep = &e16T[(q * 64 + lane) * ES];
        float acc = 0.f;
#pragma unroll
        for (int t0 = 0; t0 < TT; t0 += 8) {
          H8 bp = *(const H8*)&betas_w[wv * 64 + t0];   // broadcast read
          H8 ev = *(const H8*)(ep + t0);
          acc = dot8(bp, ev, acc);
        }
        ct[q] = acc;
      }
      ctx[wv * 64 + lane] = ct[wv];
      ((u16*)ctx16p)[wv * 64 + lane] = f2h(ct[wv]);

      // ytil dot reduces fully within the wave
      float p = ct[0] * wt_w[lane]       + ct[1] * wt_w[64 + lane]
              + ct[2] * wt_w[128 + lane] + ct[3] * wt_w[192 + lane];
#pragma unroll
      for (int off = 32; off; off >>= 1) p += __shfl_xor(p, off, 64);
      float ytil = p + yin[(size_t)b * TT + step] * wt_w[MM] + wt_b[0];

      gates_apply(g0, g1, g2, g3, ytil);
    }
    __syncthreads();   // [2] hs16 / ctx / lpart protected for next step
  }

  // ================= finals =================
  float ctdot;
  {
    float p = ctx[j] * wt_w[j];
#pragma unroll
    for (int off = 32; off; off >>= 1) p += __shfl_xor(p, off, 64);
    if (lane == 0) red2[wv] = p;
    __syncthreads();
    ctdot = red2[0] + red2[1] + red2[2] + red2[3];
    __syncthreads();
  }

  head_store(0);   // y_Tp1 (sc_head[0] keeps it for train==0 feedback)

  const int tr = train[0];
  for (int e = 0; e < 2; ++e) {
    float g0, g1, g2, g3;
    whh_mv(g0, g1, g2, g3);
    __syncthreads();   // all hs16 reads done before gates write (R8 race fix)
    float inp = tr ? tar[(size_t)b * 2 + e] : sc_head[0];
    float ytil = ctdot + inp * wt_w[MM] + wt_b[0];
    gates_apply(g0, g1, g2, g3, ytil);
    __syncthreads();
    head_store(1 + e);
  }
}

extern "C" void kernel_launch(void* const* d_in, const int* in_sizes, int n_in,
                              void* d_out, int out_size, void* d_ws, size_t ws_size,
                              hipStream_t stream) {
  const float* E     = (const float*)d_in[0];
  const float* yin   = (const float*)d_in[1];
  const float* tar   = (const float*)d_in[2];
  const int*   train = (const int*)d_in[3];
  const float* Wd_w  = (const float*)d_in[4];
  const float* Wd_b  = (const float*)d_in[5];
  const float* Ud_w  = (const float*)d_in[6];
  const float* vd_w  = (const float*)d_in[7];
  const float* wt_w  = (const float*)d_in[8];
  const float* wt_b  = (const float*)d_in[9];
  const float* Wy_w  = (const float*)d_in[10];
  const float* Wy_b  = (const float*)d_in[11];
  const float* vy_w  = (const float*)d_in[12];
  const float* vy_b  = (const float*)d_in[13];
  const float* Wih   = (const float*)d_in[14];
  const float* Whh   = (const float*)d_in[15];
  const float* bih   = (const float*)d_in[16];
  const float* bhh   = (const float*)d_in[17];

  float* out = (float*)d_out;

  if (ws_size >= WQ_BYTES) {
    u16* wq = (u16*)d_ws;
    prep_w<<<dim3(WQ_ELEMS / 256), dim3(256), 0, stream>>>(Wd_w, Whh, Wy_w, wq);
    scan_kernel<1><<<dim3(BB), dim3(256), 0, stream>>>(
        E, yin, tar, train, wq + WD16_OFF, Wd_b, Ud_w, vd_w, wt_w, wt_b,
        wq + WY16_OFF, Wy_b, vy_w, vy_b, Wih, wq + WHH16_OFF, bih, bhh, out);
  } else {
    scan_kernel<0><<<dim3(BB), dim3(256), 0, stream>>>(
        E, yin, tar, train, Wd_w, Wd_b, Ud_w, vd_w, wt_w, wt_b,
        Wy_w, Wy_b, vy_w, vy_b, Wih, Whh, bih, bhh, out);
  }

  (void)in_sizes; (void)n_in; (void)out_size;
}